// Round 9
// baseline (772.684 us; speedup 1.0000x reference)
//
#include <hip/hip_runtime.h>
#include <stdint.h>

// SpikingNeuralNetwork: B=32, S=4096, D=512, H=256, OUT=128
// MEASUREMENT ROUND. A (snn_produce) and B (snn_scan) are byte-identical to
// round 8 (total 467.5us = F(255.6) + A + B, A+B ~= 212, split unknown —
// both below the 158us top-5 cutoff). Appended: two probe kernels that
// write only to ws scratch:
//   snn_produce2 = A's body 2x (rep 1 uses f+512 to defeat CSE) -> dur ~= 2A
//   snn_scan2    = B with 128-chunk wrapped scan (2x serial work) -> dur ~= 2B
// Whichever is >=~80us surfaces in the top-5 WITH COUNTERS at 2x scale,
// telling us which phase owns the 212us and why. d_out path (memset -> A ->
// B) is unchanged; probes run after and touch only ws+8MB / ws+16MB.

#define S_LEN 4096
#define D_DIM 512
#define H_DIM 256
#define O_DIM 128
#define B_SZ  32

#define NPROD 1024              // producer blocks (4 s-rows each)
#define CH    64                // scan steps per chunk
#define NCH   (S_LEN / CH)      // 64 chunks
#define ROWS  (CH / 4)          // 16 float4-rows per chunk

typedef const __attribute__((address_space(1))) void  glob_void;
typedef       __attribute__((address_space(3))) void  lds_void;

// One LIF step, fused form (bit-exact to reference):
#define LIF_STEP(IC) {                          \
    float ict = sp2 ? 0.f : (IC);               \
    float tt  = fmaf(0.95f, u, ict);            \
    u   = sp1 ? 0.f : tt;                       \
    bool sp = (u >= 1.0f);                      \
    cnt += sp ? 1 : 0;                          \
    sp2 = sp1; sp1 = sp; }

#define ACC4(A, V) { A.x += V.x; A.y += V.y; A.z += V.z; A.w += V.w; }

// ----------------------------------------------------------------------
// Kernel A: unchanged from round 8.
__global__ __launch_bounds__(256)
void snn_produce(const float4* __restrict__ x4,
                 const float*  __restrict__ iw,
                 float4*       __restrict__ cur4) {   // packed [f][h], 4 MB
    __shared__ __attribute__((aligned(16))) float4 slab[4][512];  // 4 x 8 KB ring
    __shared__ float4 xm[512];               // 4 s-rows x 512 f32 = 8 KB
    const int t    = threadIdx.x;
    const int w    = t >> 6;                 // wave 0..3
    const int lane = t & 63;
    const int r2   = t >> 7;                 // 0..1: this thread's row pair
    const int d4   = t & 127;
    const int h    = t;
    const float inv = 1.0f / (float)B_SZ;
    const size_t bstr = (size_t)S_LEN * (D_DIM / 4);   // batch stride (float4)

    const int f = (int)blockIdx.x;           // float4-row 0..1023
    const float4* sbase = x4 + (size_t)(4 * f) * (D_DIM / 4);

    auto issue = [&](int b) {
        const float4* g = sbase + (size_t)b * bstr + w * 128 + lane;
        __builtin_amdgcn_global_load_lds((glob_void*)g,
                                         (lds_void*)&slab[b & 3][w * 128 + lane],
                                         16, 0, 0);
        __builtin_amdgcn_global_load_lds((glob_void*)(g + 64),
                                         (lds_void*)&slab[b & 3][w * 128 + 64 + lane],
                                         16, 0, 0);
    };

    issue(0); issue(1); issue(2);            // prefetch depth 3

    float4 a0 = make_float4(0.f, 0.f, 0.f, 0.f);
    float4 a1 = make_float4(0.f, 0.f, 0.f, 0.f);
    for (int b = 0; b < B_SZ; ++b) {
        if (b < B_SZ - 2)       asm volatile("s_waitcnt vmcnt(4)" ::: "memory");
        else if (b == B_SZ - 2) asm volatile("s_waitcnt vmcnt(2)" ::: "memory");
        else                    asm volatile("s_waitcnt vmcnt(0)" ::: "memory");
        __builtin_amdgcn_s_barrier();
        __builtin_amdgcn_sched_barrier(0);
        if (b + 3 < B_SZ) issue(b + 3);
        float4 v0 = slab[b & 3][r2 * 128 + d4];          // row r2
        float4 v1 = slab[b & 3][(r2 + 2) * 128 + d4];    // row r2+2
        ACC4(a0, v0);
        ACC4(a1, v1);
        asm volatile("s_waitcnt lgkmcnt(0)" ::: "memory");
        __builtin_amdgcn_sched_barrier(0);
    }

    a0.x *= inv; a0.y *= inv; a0.z *= inv; a0.w *= inv;
    a1.x *= inv; a1.y *= inv; a1.z *= inv; a1.w *= inv;
    xm[r2 * 128 + d4]       = a0;
    xm[(r2 + 2) * 128 + d4] = a1;
    __syncthreads();

    float acc2[4] = {0.f, 0.f, 0.f, 0.f};
    for (int d4i = 0; d4i < D_DIM / 4; ++d4i) {
        const int d = d4i * 4;
        float w0 = iw[(d + 0) * H_DIM + h];
        float w1 = iw[(d + 1) * H_DIM + h];
        float w2 = iw[(d + 2) * H_DIM + h];
        float w3 = iw[(d + 3) * H_DIM + h];
        #pragma unroll
        for (int r = 0; r < 4; ++r) {
            float4 xv = xm[r * 128 + d4i];
            acc2[r] += xv.x * w0 + xv.y * w1 + xv.z * w2 + xv.w * w3;
        }
    }
    cur4[(size_t)f * H_DIM + h] = make_float4(acc2[0], acc2[1], acc2[2], acc2[3]);
}

// ----------------------------------------------------------------------
// Kernel B: unchanged from round 8.
__global__ __launch_bounds__(64)
void snn_scan(const float4* __restrict__ cur4,
              const float*  __restrict__ hw,
              float*        __restrict__ out) {
    __shared__ __attribute__((aligned(16))) float4 lbuf[3][ROWS * 64];  // 3x16KB
    __shared__ float cl[64];
    const int lane  = threadIdx.x;
    const int hbase = (int)blockIdx.x * 64;

    auto stage = [&](int c, int idx) {
        #pragma unroll
        for (int r = 0; r < ROWS; ++r) {
            const float4* g = cur4 + (size_t)(c * ROWS + r) * H_DIM + hbase + lane;
            __builtin_amdgcn_global_load_lds((glob_void*)g,
                                             (lds_void*)&lbuf[idx][r * 64 + lane],
                                             16, 0, 0);
        }
    };

    float u = 0.f;
    int   cnt = 0;
    bool  sp1 = false, sp2 = false;

    stage(0, 0);
    stage(1, 1);
    int rd = 0, st = 2;
    for (int c = 0; c < NCH; ++c) {
        if (c + 2 < NCH) {
            stage(c + 2, st);
            st = (st == 2) ? 0 : st + 1;
            asm volatile("s_waitcnt vmcnt(32)" ::: "memory");
        } else if (c + 1 < NCH) {
            asm volatile("s_waitcnt vmcnt(16)" ::: "memory");
        } else {
            asm volatile("s_waitcnt vmcnt(0)" ::: "memory");
        }
        __builtin_amdgcn_sched_barrier(0);

        const float4* lb = &lbuf[rd][0];
        rd = (rd == 2) ? 0 : rd + 1;
        float4 v[ROWS];
        #pragma unroll
        for (int r = 0; r < ROWS; ++r) v[r] = lb[r * 64 + lane];
        __builtin_amdgcn_sched_barrier(0);

        #pragma unroll
        for (int r = 0; r < ROWS; ++r) {
            LIF_STEP(v[r].x); LIF_STEP(v[r].y); LIF_STEP(v[r].z); LIF_STEP(v[r].w);
        }
    }

    __syncthreads();
    cl[lane] = (float)cnt;
    __syncthreads();
    float a0 = 0.f, a1 = 0.f;
    #pragma unroll 8
    for (int k = 0; k < 64; ++k) {
        float c = cl[k];
        const float* w = hw + (size_t)(hbase + k) * O_DIM;
        a0 = fmaf(c, w[lane], a0);
        a1 = fmaf(c, w[lane + 64], a1);
    }
    a0 *= (1.0f / (float)S_LEN);
    a1 *= (1.0f / (float)S_LEN);
    for (int b = 0; b < B_SZ; ++b) {
        atomicAdd(out + b * O_DIM + lane,      a0);
        atomicAdd(out + b * O_DIM + lane + 64, a1);
    }
}

// ----------------------------------------------------------------------
// PROBE A2: A's body twice (rep 1 reads rows f+512 -> no CSE possible).
// Writes only scratch cur4b. Duration ~= 2A; surfaces in top-5 with
// counters if A >= ~80us.
__global__ __launch_bounds__(256)
void snn_produce2(const float4* __restrict__ x4,
                  const float*  __restrict__ iw,
                  float4*       __restrict__ cur4b) {
    __shared__ __attribute__((aligned(16))) float4 slab[4][512];
    __shared__ float4 xm[512];
    const int t    = threadIdx.x;
    const int w    = t >> 6;
    const int lane = t & 63;
    const int r2   = t >> 7;
    const int d4   = t & 127;
    const int h    = t;
    const float inv = 1.0f / (float)B_SZ;
    const size_t bstr = (size_t)S_LEN * (D_DIM / 4);

    for (int rep = 0; rep < 2; ++rep) {
        const int f = ((int)blockIdx.x + rep * 512) & 1023;
        const float4* sbase = x4 + (size_t)(4 * f) * (D_DIM / 4);

        auto issue = [&](int b) {
            const float4* g = sbase + (size_t)b * bstr + w * 128 + lane;
            __builtin_amdgcn_global_load_lds((glob_void*)g,
                                             (lds_void*)&slab[b & 3][w * 128 + lane],
                                             16, 0, 0);
            __builtin_amdgcn_global_load_lds((glob_void*)(g + 64),
                                             (lds_void*)&slab[b & 3][w * 128 + 64 + lane],
                                             16, 0, 0);
        };

        issue(0); issue(1); issue(2);

        float4 a0 = make_float4(0.f, 0.f, 0.f, 0.f);
        float4 a1 = make_float4(0.f, 0.f, 0.f, 0.f);
        for (int b = 0; b < B_SZ; ++b) {
            if (b < B_SZ - 2)       asm volatile("s_waitcnt vmcnt(4)" ::: "memory");
            else if (b == B_SZ - 2) asm volatile("s_waitcnt vmcnt(2)" ::: "memory");
            else                    asm volatile("s_waitcnt vmcnt(0)" ::: "memory");
            __builtin_amdgcn_s_barrier();
            __builtin_amdgcn_sched_barrier(0);
            if (b + 3 < B_SZ) issue(b + 3);
            float4 v0 = slab[b & 3][r2 * 128 + d4];
            float4 v1 = slab[b & 3][(r2 + 2) * 128 + d4];
            ACC4(a0, v0);
            ACC4(a1, v1);
            asm volatile("s_waitcnt lgkmcnt(0)" ::: "memory");
            __builtin_amdgcn_sched_barrier(0);
        }

        a0.x *= inv; a0.y *= inv; a0.z *= inv; a0.w *= inv;
        a1.x *= inv; a1.y *= inv; a1.z *= inv; a1.w *= inv;
        xm[r2 * 128 + d4]       = a0;
        xm[(r2 + 2) * 128 + d4] = a1;
        __syncthreads();

        float acc2[4] = {0.f, 0.f, 0.f, 0.f};
        for (int d4i = 0; d4i < D_DIM / 4; ++d4i) {
            const int d = d4i * 4;
            float w0 = iw[(d + 0) * H_DIM + h];
            float w1 = iw[(d + 1) * H_DIM + h];
            float w2 = iw[(d + 2) * H_DIM + h];
            float w3 = iw[(d + 3) * H_DIM + h];
            #pragma unroll
            for (int r = 0; r < 4; ++r) {
                float4 xv = xm[r * 128 + d4i];
                acc2[r] += xv.x * w0 + xv.y * w1 + xv.z * w2 + xv.w * w3;
            }
        }
        cur4b[(size_t)f * H_DIM + h] =
            make_float4(acc2[0], acc2[1], acc2[2], acc2[3]);
        __syncthreads();                      // slab/xm safe for next rep
    }
}

// ----------------------------------------------------------------------
// PROBE B2: B with 128 wrapped chunk iterations (2x serial scan work).
// Writes only scratch out2. Duration ~= 2B; surfaces in top-5 with
// counters if B >= ~80us.
__global__ __launch_bounds__(64)
void snn_scan2(const float4* __restrict__ cur4,
               const float*  __restrict__ hw,
               float*        __restrict__ out2) {
    __shared__ __attribute__((aligned(16))) float4 lbuf[3][ROWS * 64];
    __shared__ float cl[64];
    const int lane  = threadIdx.x;
    const int hbase = (int)blockIdx.x * 64;
    const int NT    = 2 * NCH;               // 128 chunk iterations

    auto stage = [&](int c, int idx) {
        #pragma unroll
        for (int r = 0; r < ROWS; ++r) {
            const float4* g = cur4 + (size_t)(c * ROWS + r) * H_DIM + hbase + lane;
            __builtin_amdgcn_global_load_lds((glob_void*)g,
                                             (lds_void*)&lbuf[idx][r * 64 + lane],
                                             16, 0, 0);
        }
    };

    float u = 0.f;
    int   cnt = 0;
    bool  sp1 = false, sp2 = false;

    stage(0, 0);
    stage(1, 1);
    int rd = 0, st = 2;
    for (int c = 0; c < NT; ++c) {
        if (c + 2 < NT) {
            stage((c + 2) & (NCH - 1), st);
            st = (st == 2) ? 0 : st + 1;
            asm volatile("s_waitcnt vmcnt(32)" ::: "memory");
        } else if (c + 1 < NT) {
            asm volatile("s_waitcnt vmcnt(16)" ::: "memory");
        } else {
            asm volatile("s_waitcnt vmcnt(0)" ::: "memory");
        }
        __builtin_amdgcn_sched_barrier(0);

        const float4* lb = &lbuf[rd][0];
        rd = (rd == 2) ? 0 : rd + 1;
        float4 v[ROWS];
        #pragma unroll
        for (int r = 0; r < ROWS; ++r) v[r] = lb[r * 64 + lane];
        __builtin_amdgcn_sched_barrier(0);

        #pragma unroll
        for (int r = 0; r < ROWS; ++r) {
            LIF_STEP(v[r].x); LIF_STEP(v[r].y); LIF_STEP(v[r].z); LIF_STEP(v[r].w);
        }
    }

    __syncthreads();
    cl[lane] = (float)cnt;
    __syncthreads();
    float a0 = 0.f, a1 = 0.f;
    #pragma unroll 8
    for (int k = 0; k < 64; ++k) {
        float c = cl[k];
        const float* w = hw + (size_t)(hbase + k) * O_DIM;
        a0 = fmaf(c, w[lane], a0);
        a1 = fmaf(c, w[lane + 64], a1);
    }
    a0 *= (1.0f / (float)S_LEN);
    a1 *= (1.0f / (float)S_LEN);
    for (int b = 0; b < B_SZ; ++b) {
        atomicAdd(out2 + b * O_DIM + lane,      a0);
        atomicAdd(out2 + b * O_DIM + lane + 64, a1);
    }
}

extern "C" void kernel_launch(void* const* d_in, const int* in_sizes, int n_in,
                              void* d_out, int out_size, void* d_ws, size_t ws_size,
                              hipStream_t stream) {
    const float4* x4 = (const float4*)d_in[0];       // [32,4096,512] f32
    const float*  iw = (const float*) d_in[1];       // [512,256] f32
    const float*  hw = (const float*) d_in[2];       // [256,128] f32
    float* out    = (float*)d_out;                   // [32,128] f32
    float4* cur4  = (float4*)d_ws;                   // [1024][256] float4 = 4 MB
    float4* cur4b = (float4*)((char*)d_ws + (size_t) 8 * 1024 * 1024);
    float*  out2  = (float*) ((char*)d_ws + (size_t)16 * 1024 * 1024);

    (void)hipMemsetAsync(out, 0, B_SZ * O_DIM * sizeof(float), stream);
    hipLaunchKernelGGL(snn_produce, dim3(NPROD), dim3(256), 0, stream,
                       x4, iw, cur4);
    hipLaunchKernelGGL(snn_scan, dim3(4), dim3(64), 0, stream,
                       cur4, hw, out);
    // ---- probes (scratch-only) ----
    hipLaunchKernelGGL(snn_produce2, dim3(NPROD), dim3(256), 0, stream,
                       x4, iw, cur4b);
    hipLaunchKernelGGL(snn_scan2, dim3(4), dim3(64), 0, stream,
                       cur4, hw, out2);
}

// Round 10
// 401.103 us; speedup vs baseline: 1.9264x; 1.9264x over previous
//
#include <hip/hip_runtime.h>
#include <stdint.h>

// SpikingNeuralNetwork: B=32, S=4096, D=512, H=256, OUT=128
// Round-10: segment-parallel speculative LIF scan.
//
// Round-9 probe ground truth: A (produce) ~66us, B (scan) ~86us, harness
// fills ~322us fixed. B is pure serial-chain latency (4096 dependent
// fma->cndmask steps, VALUBusy ~11% on its 4 CUs, 89% stall). Fix is
// algorithmic: SPIKES ARE RENEWAL POINTS. After a spike u is reset to
// exactly 0.0f and (sp1,sp2) is determined by the spike pattern, so a
// segment scanned speculatively from (u=0, no-spike history) starting 256
// steps early becomes BIT-IDENTICAL to the true trajectory at the first
// run-in spike (membrane std ~1.3 vs threshold 1.0 -> spikes every few
// steps; P(no spike in 256 steps) negligible; residual otherwise ~1e-6).
// Spike counts are integers and additive across segments -> exact combine.
//
// Kernel A (snn_produce): unchanged from round 8 (~66us).
// Kernel B1 (snn_scan_seg, 64 blocks = 16 seg x 4 hgrp, 64 lanes): lane =
//   neuron. Segment seg commits steps [256*seg, 256*(seg+1)); seg>0 runs in
//   from 256*(seg-1) speculatively. <=512 serial steps/lane (8x less than
//   4096). Same 3-ring global_load_lds staging + vmcnt(32) pipeline as the
//   verified R8 scan; count gated to committed chunks; integer counts
//   atomicAdd'ed to cnt_g[256] (device-scope, exact).
// Kernel B2 (snn_proj, 4 blocks x 64): R8's epilogue arithmetic VERBATIM
//   (same ascending-k fmaf chain, same 1/S scale, same 4 atomicAdds per out
//   element), sourcing cl[k] from cnt_g totals.
// LIF recurrence / mean / GEMV arithmetic bit-identical to rounds 0-9.

#define S_LEN 4096
#define D_DIM 512
#define H_DIM 256
#define O_DIM 128
#define B_SZ  32

#define NPROD 1024              // producer blocks (4 s-rows each)
#define CH    64                // scan steps per chunk
#define NCH   (S_LEN / CH)      // 64 chunks total
#define ROWS  (CH / 4)          // 16 float4-rows per chunk
#define NSEG  16                // scan segments (256 committed steps each)
#define SEGC  4                 // chunks per segment (256/64)

typedef const __attribute__((address_space(1))) void  glob_void;
typedef       __attribute__((address_space(3))) void  lds_void;

// One LIF step, fused form (bit-exact to reference); COM gates counting
// (state update identical in run-in and committed regions):
#define LIF_STEP(IC, COM) {                     \
    float ict = sp2 ? 0.f : (IC);               \
    float tt  = fmaf(0.95f, u, ict);            \
    u   = sp1 ? 0.f : tt;                       \
    bool sp = (u >= 1.0f);                      \
    cnt += sp ? (COM) : 0;                      \
    sp2 = sp1; sp1 = sp; }

#define ACC4(A, V) { A.x += V.x; A.y += V.y; A.z += V.z; A.w += V.w; }

// ----------------------------------------------------------------------
// Kernel A: unchanged from round 8.
__global__ __launch_bounds__(256)
void snn_produce(const float4* __restrict__ x4,
                 const float*  __restrict__ iw,
                 float4*       __restrict__ cur4) {   // packed [f][h], 4 MB
    __shared__ __attribute__((aligned(16))) float4 slab[4][512];  // 4 x 8 KB ring
    __shared__ float4 xm[512];               // 4 s-rows x 512 f32 = 8 KB
    const int t    = threadIdx.x;
    const int w    = t >> 6;                 // wave 0..3
    const int lane = t & 63;
    const int r2   = t >> 7;                 // 0..1: this thread's row pair
    const int d4   = t & 127;
    const int h    = t;
    const float inv = 1.0f / (float)B_SZ;
    const size_t bstr = (size_t)S_LEN * (D_DIM / 4);   // batch stride (float4)

    const int f = (int)blockIdx.x;           // float4-row 0..1023
    const float4* sbase = x4 + (size_t)(4 * f) * (D_DIM / 4);

    auto issue = [&](int b) {
        const float4* g = sbase + (size_t)b * bstr + w * 128 + lane;
        __builtin_amdgcn_global_load_lds((glob_void*)g,
                                         (lds_void*)&slab[b & 3][w * 128 + lane],
                                         16, 0, 0);
        __builtin_amdgcn_global_load_lds((glob_void*)(g + 64),
                                         (lds_void*)&slab[b & 3][w * 128 + 64 + lane],
                                         16, 0, 0);
    };

    issue(0); issue(1); issue(2);            // prefetch depth 3

    float4 a0 = make_float4(0.f, 0.f, 0.f, 0.f);
    float4 a1 = make_float4(0.f, 0.f, 0.f, 0.f);
    for (int b = 0; b < B_SZ; ++b) {
        if (b < B_SZ - 2)       asm volatile("s_waitcnt vmcnt(4)" ::: "memory");
        else if (b == B_SZ - 2) asm volatile("s_waitcnt vmcnt(2)" ::: "memory");
        else                    asm volatile("s_waitcnt vmcnt(0)" ::: "memory");
        __builtin_amdgcn_s_barrier();
        __builtin_amdgcn_sched_barrier(0);
        if (b + 3 < B_SZ) issue(b + 3);
        float4 v0 = slab[b & 3][r2 * 128 + d4];          // row r2
        float4 v1 = slab[b & 3][(r2 + 2) * 128 + d4];    // row r2+2
        ACC4(a0, v0);
        ACC4(a1, v1);
        asm volatile("s_waitcnt lgkmcnt(0)" ::: "memory");
        __builtin_amdgcn_sched_barrier(0);
    }

    a0.x *= inv; a0.y *= inv; a0.z *= inv; a0.w *= inv;
    a1.x *= inv; a1.y *= inv; a1.z *= inv; a1.w *= inv;
    xm[r2 * 128 + d4]       = a0;
    xm[(r2 + 2) * 128 + d4] = a1;
    __syncthreads();

    float acc2[4] = {0.f, 0.f, 0.f, 0.f};
    for (int d4i = 0; d4i < D_DIM / 4; ++d4i) {
        const int d = d4i * 4;
        float w0 = iw[(d + 0) * H_DIM + h];
        float w1 = iw[(d + 1) * H_DIM + h];
        float w2 = iw[(d + 2) * H_DIM + h];
        float w3 = iw[(d + 3) * H_DIM + h];
        #pragma unroll
        for (int r = 0; r < 4; ++r) {
            float4 xv = xm[r * 128 + d4i];
            acc2[r] += xv.x * w0 + xv.y * w1 + xv.z * w2 + xv.w * w3;
        }
    }
    cur4[(size_t)f * H_DIM + h] = make_float4(acc2[0], acc2[1], acc2[2], acc2[3]);
}

// ----------------------------------------------------------------------
// Kernel B1: segment-parallel speculative LIF scan.
// Block (seg, hgrp): seg = blockIdx>>2 (0..15), hgrp = blockIdx&3.
// seg 0: chunks 0..3, all committed (u=0 IS the true init — no run-in).
// seg>0: chunks 4(seg-1)..4(seg-1)+7; first 4 = speculative run-in from
//        (u=0, sp1=sp2=false), last 4 = committed (state bit-exact after
//        the first run-in spike; see header).
__global__ __launch_bounds__(64)
void snn_scan_seg(const float4* __restrict__ cur4,
                  uint32_t*     __restrict__ cnt_g) {
    __shared__ __attribute__((aligned(16))) float4 lbuf[3][ROWS * 64];  // 3x16KB
    const int lane  = threadIdx.x;           // one neuron chain per lane
    const int hgrp  = (int)blockIdx.x & 3;
    const int seg   = (int)blockIdx.x >> 2;
    const int hbase = hgrp * 64;
    const int c0    = seg ? (seg - 1) * SEGC : 0;  // first global chunk
    const int NT    = seg ? 2 * SEGC : SEGC;       // chunks to process
    const int cfrom = seg ? SEGC : 0;              // first committed chunk

    // 16 x 16B DMA for local chunk ci into ring buffer idx.
    auto stage = [&](int ci, int idx) {
        #pragma unroll
        for (int r = 0; r < ROWS; ++r) {
            const float4* g = cur4 +
                (size_t)((c0 + ci) * ROWS + r) * H_DIM + hbase + lane;
            __builtin_amdgcn_global_load_lds((glob_void*)g,
                                             (lds_void*)&lbuf[idx][r * 64 + lane],
                                             16, 0, 0);
        }
    };

    float u = 0.f;
    int   cnt = 0;
    bool  sp1 = false, sp2 = false;

    stage(0, 0);
    stage(1, 1);
    int rd = 0, st = 2;
    for (int c = 0; c < NT; ++c) {
        if (c + 2 < NT) {
            stage(c + 2, st);
            st = (st == 2) ? 0 : st + 1;
            asm volatile("s_waitcnt vmcnt(32)" ::: "memory");
        } else if (c + 1 < NT) {
            asm volatile("s_waitcnt vmcnt(16)" ::: "memory");
        } else {
            asm volatile("s_waitcnt vmcnt(0)" ::: "memory");
        }
        __builtin_amdgcn_sched_barrier(0);

        const float4* lb = &lbuf[rd][0];
        rd = (rd == 2) ? 0 : rd + 1;
        float4 v[ROWS];
        #pragma unroll
        for (int r = 0; r < ROWS; ++r) v[r] = lb[r * 64 + lane];
        __builtin_amdgcn_sched_barrier(0);

        const int com = (c >= cfrom) ? 1 : 0;    // count only committed chunks
        #pragma unroll
        for (int r = 0; r < ROWS; ++r) {
            LIF_STEP(v[r].x, com); LIF_STEP(v[r].y, com);
            LIF_STEP(v[r].z, com); LIF_STEP(v[r].w, com);
        }
    }

    // Exact integer combine across segments (device-scope atomic).
    atomicAdd(&cnt_g[hbase + lane], (uint32_t)cnt);
}

// ----------------------------------------------------------------------
// Kernel B2: projection epilogue — R8's arithmetic verbatim, counts from
// cnt_g totals (kernel-boundary coherence).
__global__ __launch_bounds__(64)
void snn_proj(const uint32_t* __restrict__ cnt_g,
              const float*    __restrict__ hw,
              float*          __restrict__ out) {
    __shared__ float cl[64];
    const int lane  = threadIdx.x;
    const int hbase = (int)blockIdx.x * 64;

    cl[lane] = (float)cnt_g[hbase + lane];
    __syncthreads();
    float a0 = 0.f, a1 = 0.f;
    #pragma unroll 8
    for (int k = 0; k < 64; ++k) {
        float c = cl[k];
        const float* w = hw + (size_t)(hbase + k) * O_DIM;
        a0 = fmaf(c, w[lane], a0);
        a1 = fmaf(c, w[lane + 64], a1);
    }
    a0 *= (1.0f / (float)S_LEN);
    a1 *= (1.0f / (float)S_LEN);
    for (int b = 0; b < B_SZ; ++b) {
        atomicAdd(out + b * O_DIM + lane,      a0);
        atomicAdd(out + b * O_DIM + lane + 64, a1);
    }
}

extern "C" void kernel_launch(void* const* d_in, const int* in_sizes, int n_in,
                              void* d_out, int out_size, void* d_ws, size_t ws_size,
                              hipStream_t stream) {
    const float4* x4 = (const float4*)d_in[0];       // [32,4096,512] f32
    const float*  iw = (const float*) d_in[1];       // [512,256] f32
    const float*  hw = (const float*) d_in[2];       // [256,128] f32
    float* out     = (float*)d_out;                  // [32,128] f32
    float4* cur4   = (float4*)d_ws;                  // [1024][256] float4 = 4 MB
    uint32_t* cnt_g = (uint32_t*)((char*)d_ws + (size_t)8 * 1024 * 1024);

    (void)hipMemsetAsync(out,   0, B_SZ * O_DIM * sizeof(float), stream);
    (void)hipMemsetAsync(cnt_g, 0, H_DIM * sizeof(uint32_t), stream);
    hipLaunchKernelGGL(snn_produce, dim3(NPROD), dim3(256), 0, stream,
                       x4, iw, cur4);
    hipLaunchKernelGGL(snn_scan_seg, dim3(4 * NSEG), dim3(64), 0, stream,
                       cur4, cnt_g);
    hipLaunchKernelGGL(snn_proj, dim3(4), dim3(64), 0, stream,
                       cnt_g, hw, out);
}